// Round 4
// baseline (154.544 us; speedup 1.0000x reference)
//
#include <hip/hip_runtime.h>

#define NPRI 10647
#define BB 16
#define LL 50
#define OBJ_BLOCKS 666          // ceil(16*10647 / 256)
#define CHO_BLOCKS (BB * LL)    // 800
#define TOT_BLOCKS (OBJ_BLOCKS + CHO_BLOCKS)

// 0.5 - 2^-26: exact post-rounding threshold. round_rn(inter/denom) >= 0.5f
// <=> inter >= denom * SUPP_C (exact: 24-bit x 26-bit significand product is
// exact in double; tie at 0.5-2^-26 rounds to even = 0.5 => suppressed).
#define SUPP_C 0.49999998509883880615234375

// All anchor-derived constants folded at COMPILE TIME in double, matching
// numpy's python-float math exactly (power-of-2 scale commutes with rounding).
__device__ __constant__ double c_hw[3][3] = {
    {0.5*(116.0/416.0), 0.5*(156.0/416.0), 0.5*(373.0/416.0)},
    {0.5*( 30.0/416.0), 0.5*( 62.0/416.0), 0.5*( 59.0/416.0)},
    {0.5*( 10.0/416.0), 0.5*( 16.0/416.0), 0.5*( 33.0/416.0)}};
__device__ __constant__ double c_hh[3][3] = {
    {0.5*( 90.0/416.0), 0.5*(198.0/416.0), 0.5*(326.0/416.0)},
    {0.5*( 61.0/416.0), 0.5*( 45.0/416.0), 0.5*(119.0/416.0)},
    {0.5*( 23.0/416.0), 0.5*( 30.0/416.0), 0.5*( 23.0/416.0)}};
__device__ __constant__ float c_pwf[3][3] = {
    {(float)(116.0/416.0), (float)(156.0/416.0), (float)(373.0/416.0)},
    {(float)( 30.0/416.0), (float)( 62.0/416.0), (float)( 59.0/416.0)},
    {(float)( 10.0/416.0), (float)( 16.0/416.0), (float)( 33.0/416.0)}};
__device__ __constant__ float c_phf[3][3] = {
    {(float)( 90.0/416.0), (float)(198.0/416.0), (float)(326.0/416.0)},
    {(float)( 61.0/416.0), (float)( 45.0/416.0), (float)(119.0/416.0)},
    {(float)( 23.0/416.0), (float)( 30.0/416.0), (float)( 23.0/416.0)}};
__device__ __constant__ float c_awf[3][3] = {{116,156,373},{30,62,59},{10,16,33}};
__device__ __constant__ float c_ahf[3][3] = {{90,198,326},{61,45,119},{23,30,23}};
// 1 / (B*A*S*S) per level
__device__ __constant__ double c_wObj[3] = {1.0/8112.0, 1.0/32448.0, 1.0/129792.0};

// per-branch constant divisors -> compiler emits magic-mul, no runtime idiv
__device__ inline void decode_prior(int n, int& level, int& S, int& ii, int& jj,
                                    int& aa, int& off) {
    if (n < 507)        { level = 0; S = 13; int c = n / 3;            aa = n - 3*c;            jj = c % 13; ii = c / 13; off = 0;  }
    else if (n < 2535)  { level = 1; S = 26; int nn = n - 507;  int c = nn / 3; aa = nn - 3*c; jj = c % 26; ii = c / 26; off = 13; }
    else                { level = 2; S = 52; int nn = n - 2535; int c = nn / 3; aa = nn - 3*c; jj = c % 52; ii = c / 52; off = 39; }
}

// ---------------------------------------------------------------- assign (one block per (b,l))
__global__ __launch_bounds__(256) void assign_kernel(
    const float* __restrict__ labels, int* __restrict__ idxArr,
    float4* __restrict__ tcoord, int* __restrict__ counter) {
    __shared__ double s_cx[91];     // (idx+0.5)/S for S in {13,26,52}
    __shared__ float  s_iou[NPRI];  // 42.6 KB
    __shared__ float  s_w[4];
    __shared__ int    s_wsum[4];

    int tid = threadIdx.x, lane = tid & 63, wid = tid >> 6;
    int gi  = blockIdx.x;
    if (gi == 0 && tid == 0) *counter = 0;   // for loss kernel's completion ticket
    const float* lab = labels + gi * 5;
    float cls = lab[0];
    if (tid == 0) idxArr[gi] = -1;
    if (cls < 0.0f) return;   // uniform per block, before any __syncthreads

    if (tid < 91) {   // double-precision center table, matching numpy
        int S, idx;
        if (tid < 13)      { S = 13; idx = tid; }
        else if (tid < 39) { S = 26; idx = tid - 13; }
        else               { S = 52; idx = tid - 39; }
        s_cx[tid] = ((double)idx + 0.5) / (double)S;
    }

    float bx = lab[1], by = lab[2], bw = lab[3], bh = lab[4];
    float bxe  = __fadd_rn(bx, bw), bye = __fadd_rn(by, bh);
    float bwbh = __fmul_rn(bw, bh);
    __syncthreads();

    float lmax = -3.0e38f;
    for (int n = tid; n < NPRI; n += 256) {
        int level, S, ii, jj, aa, off;
        decode_prior(n, level, S, ii, jj, aa, off);
        float px  = (float)(s_cx[off + jj] - c_hw[level][aa]);
        float py  = (float)(s_cx[off + ii] - c_hh[level][aa]);
        float pwf = c_pwf[level][aa], phf = c_phf[level][aa];
        float pxe = __fadd_rn(px, pwf), pye = __fadd_rn(py, phf);
        float pwph = __fmul_rn(pwf, phf);
        float ix = fmaxf(px, bx), iy = fmaxf(py, by);
        float ax = fminf(pxe, bxe), ay = fminf(pye, bye);
        float iw = fmaxf(__fsub_rn(ax, ix), 0.0f);
        float ih = fmaxf(__fsub_rn(ay, iy), 0.0f);
        float inter = __fmul_rn(iw, ih);
        float denom = __fsub_rn(__fadd_rn(pwph, bwbh), inter);
        float iou = __fdiv_rn(inter, denom);
        s_iou[n] = iou;
        lmax = fmaxf(lmax, iou);
    }
    // wave-level max reduce (6 shfl steps), then 4-way LDS combine
    for (int d = 1; d < 64; d <<= 1) lmax = fmaxf(lmax, __shfl_xor(lmax, d));
    if (lane == 0) s_w[wid] = lmax;
    __syncthreads();   // also publishes s_iou
    float m = fmaxf(fmaxf(s_w[0], s_w[1]), fmaxf(s_w[2], s_w[3]));

    // tie count per contiguous chunk (index order)
    const int CH = 42;   // 256*42 >= NPRI
    int start = tid * CH;
    int end   = min(start + CH, NPRI);
    int cnt = 0;
    for (int n = start; n < end; ++n) cnt += (s_iou[n] == m) ? 1 : 0;

    // wave-level inclusive scan (shfl_up), wave offsets via LDS
    int incl = cnt;
    for (int d = 1; d < 64; d <<= 1) {
        int v = __shfl_up(incl, d);
        if (lane >= d) incl += v;
    }
    if (lane == 63) s_wsum[wid] = incl;
    __syncthreads();
    int woff = 0, k = 0;
    for (int w = 0; w < 4; ++w) { int v = s_wsum[w]; k += v; if (w < wid) woff += v; }
    int rank = (k - 1) / 2 + 1;
    int pre  = woff + incl - cnt;   // exclusive prefix

    if (pre < rank && rank <= pre + cnt) {
        int r = rank - pre;
        int sel = -1;
        for (int n = start; n < end; ++n)
            if (s_iou[n] == m && --r == 0) { sel = n; break; }
        int level, S, ii, jj, aa, off;
        decode_prior(sel, level, S, ii, jj, aa, off);
        float Sf = (float)S, colf = (float)jj, rowf = (float)ii;
        float dx = __fsub_rn(__fmul_rn(__fadd_rn(bx, __fmul_rn(0.5f, bw)), Sf), colf);
        float dy = __fsub_rn(__fmul_rn(__fadd_rn(by, __fmul_rn(0.5f, bh)), Sf), rowf);
        dx = fminf(fmaxf(dx, 1e-6f), 0.999999f);
        dy = fminf(fmaxf(dy, 1e-6f), 0.999999f);
        float t0 = logf(__fdiv_rn(dx, __fsub_rn(1.0f, dx)));
        float t1 = logf(__fdiv_rn(dy, __fsub_rn(1.0f, dy)));
        float t2 = logf(__fdiv_rn(__fmul_rn(bw, 416.0f), c_awf[level][aa]));
        float t3 = logf(__fdiv_rn(__fmul_rn(bh, 416.0f), c_ahf[level][aa]));
        tcoord[gi] = make_float4(t0, t1, t2, t3);
        idxArr[gi] = sel;
    }
}

// ---------------------------------------------------------------- fused loss + finalize
// blocks [0, OBJ_BLOCKS): obj BCE over (b,n); suppression recomputed with the
//   exact div-free comparison over a COMPACTED valid-label list.
// blocks [OBJ_BLOCKS, TOT_BLOCKS): coord+class for label gi, lane-parallel.
// Last-finished block (completion ticket) reduces all partials -> d_out.
__global__ __launch_bounds__(256) void loss_kernel(
    const float* __restrict__ o0, const float* __restrict__ o1, const float* __restrict__ o2,
    const float* __restrict__ labels, const int* __restrict__ idxArr,
    const float4* __restrict__ tcoord,
    double* __restrict__ pObj, double* __restrict__ pCoord, double* __restrict__ pClass,
    int* __restrict__ counter, float* __restrict__ out) {
    __shared__ double s_cx[91];
    __shared__ float  s_lbx[2][LL], s_lby[2][LL], s_lxe[2][LL], s_lye[2][LL], s_lar[2][LL];
    __shared__ int    s_lidx[2][LL];
    __shared__ int    s_lcnt[2];
    __shared__ double s_red[256];
    __shared__ int    s_last;
    int tid = threadIdx.x, lane = tid & 63, wid = tid >> 6;

    if (blockIdx.x < OBJ_BLOCKS) {
        int e0 = blockIdx.x * 256;
        int b0 = e0 / NPRI;
        int b1 = min((e0 + 255) / NPRI, BB - 1);
        if (tid < 91) {
            int S, idx;
            if (tid < 13)      { S = 13; idx = tid; }
            else if (tid < 39) { S = 26; idx = tid - 13; }
            else               { S = 52; idx = tid - 39; }
            s_cx[tid] = ((double)idx + 0.5) / (double)S;
        }
        if (wid < 2) {   // wave 0 compacts b0's labels, wave 1 b1's
            int b = wid ? b1 : b0;
            float cls = -1.0f, bx = 0, by = 0, bw = 0, bh = 0; int idx = -1;
            if (lane < LL) {
                const float* lab = labels + (b * LL + lane) * 5;
                cls = lab[0]; bx = lab[1]; by = lab[2]; bw = lab[3]; bh = lab[4];
                idx = idxArr[b * LL + lane];
            }
            bool valid = (lane < LL) && (cls >= 0.0f);
            unsigned long long mask = __ballot(valid);
            if (valid) {
                int pos = __popcll(mask & ((1ull << lane) - 1ull));
                s_lbx[wid][pos] = bx;
                s_lby[wid][pos] = by;
                s_lxe[wid][pos] = __fadd_rn(bx, bw);
                s_lye[wid][pos] = __fadd_rn(by, bh);
                s_lar[wid][pos] = __fmul_rn(bw, bh);
                s_lidx[wid][pos] = idx;
            }
            if (lane == 0) s_lcnt[wid] = __popcll(mask);
        }
        __syncthreads();

        int e = e0 + tid;
        double a = 0.0;
        if (e < BB * NPRI) {
            int b = e / NPRI, n = e - b * NPRI;
            int which = (b == b0) ? 0 : 1;
            int level, S, ii, jj, aa, off;
            decode_prior(n, level, S, ii, jj, aa, off);
            float px  = (float)(s_cx[off + jj] - c_hw[level][aa]);
            float py  = (float)(s_cx[off + ii] - c_hh[level][aa]);
            float pwf = c_pwf[level][aa], phf = c_phf[level][aa];
            float pxe = __fadd_rn(px, pwf), pye = __fadd_rn(py, phf);
            float pwph = __fmul_rn(pwf, phf);
            bool supp = false, chosen = false;
            int cnt = s_lcnt[which];
            for (int l = 0; l < cnt; ++l) {
                chosen = chosen | (s_lidx[which][l] == n);
                float ix = fmaxf(px, s_lbx[which][l]);
                float iy = fmaxf(py, s_lby[which][l]);
                float ax = fminf(pxe, s_lxe[which][l]);
                float ay = fminf(pye, s_lye[which][l]);
                float iw = fmaxf(__fsub_rn(ax, ix), 0.0f);
                float ih = fmaxf(__fsub_rn(ay, iy), 0.0f);
                float inter = __fmul_rn(iw, ih);
                float denom = __fsub_rn(__fadd_rn(pwph, s_lar[which][l]), inter);
                supp = supp | ((double)inter >= SUPP_C * (double)denom);
            }
            if (chosen || !supp) {   // masked-out entries contribute exactly 0
                int SS2 = S * S;
                const float* outp = (level == 0) ? o0 : ((level == 1) ? o1 : o2);
                float x = outp[(size_t)b * 255 * SS2 + (aa * 85 + 4) * SS2 + ii * S + jj];
                float p = 1.0f / (1.0f + expf(-x));
                float t = chosen ? 1.0f : 0.0f;
                float lp = fmaxf(logf(p), -100.0f);
                float lq = fmaxf(logf(1.0f - p), -100.0f);
                a = -(double)(t * lp + (1.0f - t) * lq) * c_wObj[level];
            }
        }
        s_red[tid] = a; __syncthreads();
        for (int s = 128; s > 0; s >>= 1) { if (tid < s) s_red[tid] += s_red[tid + s]; __syncthreads(); }
        if (tid == 0) pObj[blockIdx.x] = s_red[0];
    } else {
        int gi = blockIdx.x - OBJ_BLOCKS;
        int b  = gi / LL, lsel = gi - b * LL;
        if (tid < LL) {
            s_lidx[0][tid] = idxArr[b * LL + tid];
            s_lar[0][tid]  = labels[(b * LL + tid) * 5];
        }
        __syncthreads();
        int sel = s_lidx[0][lsel];
        int maxl = -1;
        if (sel >= 0)
            for (int l = 0; l < LL; ++l) if (s_lidx[0][l] == sel) maxl = l;
        bool active = (sel >= 0) && (maxl == lsel);   // segment_max winner

        double vc = 0.0, vk = 0.0;
        if (active) {
            int level, S, ii, jj, aa, off;
            decode_prior(sel, level, S, ii, jj, aa, off);
            int SS2 = S * S;
            const float* outp = (level == 0) ? o0 : ((level == 1) ? o1 : o2);
            const float* base = outp + (size_t)b * 255 * SS2 + aa * 85 * SS2 + ii * S + jj;
            double wObj = c_wObj[level];
            if (tid < 4) {                     // coord channels 0..3
                float4 ct = tcoord[gi];
                float ctk = (tid == 0) ? ct.x : (tid == 1) ? ct.y : (tid == 2) ? ct.z : ct.w;
                float x = base[tid * SS2];
                float d = __fsub_rn(x, ctk);
                vc = (double)__fmul_rn(d, d) * (wObj * 0.25);
            } else if (tid >= 5 && tid < 85) { // class channels 5..84
                int cc = tid - 5;
                float x = base[tid * SS2];
                float t = 0.0f;
                for (int l = 0; l < LL; ++l)
                    if (s_lidx[0][l] == sel && (int)s_lar[0][l] == cc) t = 1.0f;
                float p = 1.0f / (1.0f + expf(-x));
                float lp = fmaxf(logf(p), -100.0f);
                float lq = fmaxf(logf(1.0f - p), -100.0f);
                vk = -(double)(t * lp + (1.0f - t) * lq) * (wObj * 0.0125);
            }
        }
        s_red[tid] = vc; __syncthreads();
        for (int s = 128; s > 0; s >>= 1) { if (tid < s) s_red[tid] += s_red[tid + s]; __syncthreads(); }
        if (tid == 0) pCoord[gi] = s_red[0];
        __syncthreads();
        s_red[tid] = vk; __syncthreads();
        for (int s = 128; s > 0; s >>= 1) { if (tid < s) s_red[tid] += s_red[tid + s]; __syncthreads(); }
        if (tid == 0) pClass[gi] = s_red[0];
    }

    // ---- completion ticket: last block reduces all partials (no extra launch)
    if (tid == 0) {
        __threadfence();
        int t = atomicAdd(counter, 1);
        s_last = (t == TOT_BLOCKS - 1) ? 1 : 0;
    }
    __syncthreads();
    if (s_last) {
        __threadfence();
        double sO = 0.0, sC = 0.0, sK = 0.0;
        for (int i = tid; i < OBJ_BLOCKS; i += 256) sO += pObj[i];
        for (int i = tid; i < CHO_BLOCKS; i += 256) { sC += pCoord[i]; sK += pClass[i]; }
        s_red[tid] = sO; __syncthreads();
        for (int s = 128; s > 0; s >>= 1) { if (tid < s) s_red[tid] += s_red[tid + s]; __syncthreads(); }
        if (tid == 0) out[0] = (float)s_red[0];
        __syncthreads();
        s_red[tid] = sC; __syncthreads();
        for (int s = 128; s > 0; s >>= 1) { if (tid < s) s_red[tid] += s_red[tid + s]; __syncthreads(); }
        if (tid == 0) out[1] = (float)s_red[0];
        __syncthreads();
        s_red[tid] = sK; __syncthreads();
        for (int s = 128; s > 0; s >>= 1) { if (tid < s) s_red[tid] += s_red[tid + s]; __syncthreads(); }
        if (tid == 0) out[2] = (float)s_red[0];
    }
}

extern "C" void kernel_launch(void* const* d_in, const int* in_sizes, int n_in,
                              void* d_out, int out_size, void* d_ws, size_t ws_size,
                              hipStream_t stream) {
    const float* o0     = (const float*)d_in[0];
    const float* o1     = (const float*)d_in[1];
    const float* o2     = (const float*)d_in[2];
    const float* labels = (const float*)d_in[3];

    char* ws = (char*)d_ws;
    int*    idxArr  = (int*)   (ws);          // 800*4  = 3200
    float4* tcoord  = (float4*)(ws + 3200);   // 800*16 -> 16000
    double* pObj    = (double*)(ws + 16000);  // 666*8  -> 21328
    double* pCoord  = (double*)(ws + 21328);  // 800*8  -> 27728
    double* pClass  = (double*)(ws + 27728);  // 800*8  -> 34128
    int*    counter = (int*)   (ws + 34128);  // 4      -> 34132

    assign_kernel<<<BB * LL, 256, 0, stream>>>(labels, idxArr, tcoord, counter);
    loss_kernel<<<TOT_BLOCKS, 256, 0, stream>>>(o0, o1, o2, labels, idxArr, tcoord,
                                                pObj, pCoord, pClass, counter,
                                                (float*)d_out);
}

// Round 5
// 124.772 us; speedup vs baseline: 1.2386x; 1.2386x over previous
//
#include <hip/hip_runtime.h>

#define NPRI 10647
#define BB 16
#define LL 50
#define OBJ_BLOCKS 720          // 48 (L0) + 144 (L1) + 528 (L2) coalesced chunks
#define CHO_BLOCKS (BB * LL)    // 800
#define TOT_BLOCKS (OBJ_BLOCKS + CHO_BLOCKS)

// 0.5 - 2^-26: exact post-rounding threshold. round_rn(inter/denom) >= 0.5f
// <=> inter >= denom * SUPP_C (24-bit x 25-bit significand product is exact
// in double; tie at 0.5-2^-26 rounds to even = 0.5 => suppressed).
// Empirically validated (round-4 kernel passed with identical absmax).
#define SUPP_C 0.49999998509883880615234375

// All anchor-derived constants folded at COMPILE TIME in double, matching
// numpy's python-float math exactly (power-of-2 scale commutes with rounding).
__device__ __constant__ double c_hw[3][3] = {
    {0.5*(116.0/416.0), 0.5*(156.0/416.0), 0.5*(373.0/416.0)},
    {0.5*( 30.0/416.0), 0.5*( 62.0/416.0), 0.5*( 59.0/416.0)},
    {0.5*( 10.0/416.0), 0.5*( 16.0/416.0), 0.5*( 33.0/416.0)}};
__device__ __constant__ double c_hh[3][3] = {
    {0.5*( 90.0/416.0), 0.5*(198.0/416.0), 0.5*(326.0/416.0)},
    {0.5*( 61.0/416.0), 0.5*( 45.0/416.0), 0.5*(119.0/416.0)},
    {0.5*( 23.0/416.0), 0.5*( 30.0/416.0), 0.5*( 23.0/416.0)}};
__device__ __constant__ float c_pwf[3][3] = {
    {(float)(116.0/416.0), (float)(156.0/416.0), (float)(373.0/416.0)},
    {(float)( 30.0/416.0), (float)( 62.0/416.0), (float)( 59.0/416.0)},
    {(float)( 10.0/416.0), (float)( 16.0/416.0), (float)( 33.0/416.0)}};
__device__ __constant__ float c_phf[3][3] = {
    {(float)( 90.0/416.0), (float)(198.0/416.0), (float)(326.0/416.0)},
    {(float)( 61.0/416.0), (float)( 45.0/416.0), (float)(119.0/416.0)},
    {(float)( 23.0/416.0), (float)( 30.0/416.0), (float)( 23.0/416.0)}};
__device__ __constant__ float c_awf[3][3] = {{116,156,373},{30,62,59},{10,16,33}};
__device__ __constant__ float c_ahf[3][3] = {{90,198,326},{61,45,119},{23,30,23}};
// 1 / (B*A*S*S) per level
__device__ __constant__ double c_wObj[3] = {1.0/8112.0, 1.0/32448.0, 1.0/129792.0};

// per-branch constant divisors -> compiler emits magic-mul, no runtime idiv
__device__ inline void decode_prior(int n, int& level, int& S, int& ii, int& jj,
                                    int& aa, int& off) {
    if (n < 507)        { level = 0; S = 13; int c = n / 3;            aa = n - 3*c;            jj = c % 13; ii = c / 13; off = 0;  }
    else if (n < 2535)  { level = 1; S = 26; int nn = n - 507;  int c = nn / 3; aa = nn - 3*c; jj = c % 26; ii = c / 26; off = 13; }
    else                { level = 2; S = 52; int nn = n - 2535; int c = nn / 3; aa = nn - 3*c; jj = c % 52; ii = c / 52; off = 39; }
}

// ---------------------------------------------------------------- assign (one block per (b,l))
// Exact config from the validated 127-us run.
__global__ __launch_bounds__(256) void assign_kernel(
    const float* __restrict__ labels, int* __restrict__ idxArr,
    float4* __restrict__ tcoord) {
    __shared__ double s_cx[91];     // (idx+0.5)/S for S in {13,26,52}
    __shared__ float  s_iou[NPRI];  // 42.6 KB
    __shared__ float  s_red[256];
    __shared__ int    s_cnt[256];

    int tid = threadIdx.x;
    int gi  = blockIdx.x;
    const float* lab = labels + gi * 5;
    float cls = lab[0];
    if (tid == 0) idxArr[gi] = -1;
    if (cls < 0.0f) return;   // uniform per block, before any __syncthreads

    if (tid < 91) {   // double-precision center table, matching numpy
        int S, idx;
        if (tid < 13)      { S = 13; idx = tid; }
        else if (tid < 39) { S = 26; idx = tid - 13; }
        else               { S = 52; idx = tid - 39; }
        s_cx[tid] = ((double)idx + 0.5) / (double)S;
    }

    float bx = lab[1], by = lab[2], bw = lab[3], bh = lab[4];
    float bxe  = __fadd_rn(bx, bw), bye = __fadd_rn(by, bh);
    float bwbh = __fmul_rn(bw, bh);
    __syncthreads();

    float lmax = -3.0e38f;
    for (int n = tid; n < NPRI; n += 256) {
        int level, S, ii, jj, aa, off;
        decode_prior(n, level, S, ii, jj, aa, off);
        float px  = (float)(s_cx[off + jj] - c_hw[level][aa]);
        float py  = (float)(s_cx[off + ii] - c_hh[level][aa]);
        float pwf = c_pwf[level][aa], phf = c_phf[level][aa];
        float pxe = __fadd_rn(px, pwf), pye = __fadd_rn(py, phf);
        float pwph = __fmul_rn(pwf, phf);
        float ix = fmaxf(px, bx), iy = fmaxf(py, by);
        float ax = fminf(pxe, bxe), ay = fminf(pye, bye);
        float iw = fmaxf(__fsub_rn(ax, ix), 0.0f);
        float ih = fmaxf(__fsub_rn(ay, iy), 0.0f);
        float inter = __fmul_rn(iw, ih);
        float denom = __fsub_rn(__fadd_rn(pwph, bwbh), inter);
        float iou = __fdiv_rn(inter, denom);
        s_iou[n] = iou;
        lmax = fmaxf(lmax, iou);
    }
    s_red[tid] = lmax;
    __syncthreads();
    for (int s = 128; s > 0; s >>= 1) {
        if (tid < s) s_red[tid] = fmaxf(s_red[tid], s_red[tid + s]);
        __syncthreads();
    }
    float m = s_red[0];

    // tie count per contiguous chunk (index order)
    const int CH = 42;   // 256*42 >= NPRI
    int start = tid * CH;
    int end   = min(start + CH, NPRI);
    int cnt = 0;
    for (int n = start; n < end; ++n) cnt += (s_iou[n] == m) ? 1 : 0;

    // parallel inclusive scan (Hillis-Steele, 8 steps)
    s_cnt[tid] = cnt;
    __syncthreads();
    for (int d = 1; d < 256; d <<= 1) {
        int add = (tid >= d) ? s_cnt[tid - d] : 0;
        __syncthreads();
        s_cnt[tid] += add;
        __syncthreads();
    }
    int k    = s_cnt[255];
    int rank = (k - 1) / 2 + 1;
    int pre  = s_cnt[tid] - cnt;   // exclusive prefix

    if (pre < rank && rank <= pre + cnt) {
        int r = rank - pre;
        int sel = -1;
        for (int n = start; n < end; ++n)
            if (s_iou[n] == m && --r == 0) { sel = n; break; }
        int level, S, ii, jj, aa, off;
        decode_prior(sel, level, S, ii, jj, aa, off);
        float Sf = (float)S, colf = (float)jj, rowf = (float)ii;
        float dx = __fsub_rn(__fmul_rn(__fadd_rn(bx, __fmul_rn(0.5f, bw)), Sf), colf);
        float dy = __fsub_rn(__fmul_rn(__fadd_rn(by, __fmul_rn(0.5f, bh)), Sf), rowf);
        dx = fminf(fmaxf(dx, 1e-6f), 0.999999f);
        dy = fminf(fmaxf(dy, 1e-6f), 0.999999f);
        float t0 = logf(__fdiv_rn(dx, __fsub_rn(1.0f, dx)));
        float t1 = logf(__fdiv_rn(dy, __fsub_rn(1.0f, dy)));
        float t2 = logf(__fdiv_rn(__fmul_rn(bw, 416.0f), c_awf[level][aa]));
        float t3 = logf(__fdiv_rn(__fmul_rn(bh, 416.0f), c_ahf[level][aa]));
        tcoord[gi] = make_float4(t0, t1, t2, t3);
        idxArr[gi] = sel;
    }
}

// ---------------------------------------------------------------- fused loss
// blocks [0, OBJ_BLOCKS): obj BCE in MEMORY ORDER — one block per
//   (level, b, anchor, 256-span of spatial positions). Waves read contiguous
//   256 B of the objectness channel (fully coalesced); suppression uses the
//   exact div-free test over a compacted valid-label list in LDS.
// blocks [OBJ_BLOCKS, TOT_BLOCKS): coord+class for label gi, lane-parallel.
__global__ __launch_bounds__(256) void loss_kernel(
    const float* __restrict__ o0, const float* __restrict__ o1, const float* __restrict__ o2,
    const float* __restrict__ labels, const int* __restrict__ idxArr,
    const float4* __restrict__ tcoord,
    double* __restrict__ pObj, double* __restrict__ pCoord, double* __restrict__ pClass) {
    __shared__ double s_cx[52];
    __shared__ float  s_lbx[LL], s_lby[LL], s_lxe[LL], s_lye[LL], s_lar[LL];
    __shared__ int    s_lidx[LL];
    __shared__ int    s_lcnt;
    __shared__ int    s_cidx[LL];
    __shared__ float  s_ccls[LL];
    __shared__ double s_red[256];
    int tid = threadIdx.x, lane = tid & 63, wid = tid >> 6;

    if (blockIdx.x < OBJ_BLOCKS) {
        // ---- decode (level, b, aa, chunk)
        int bid = blockIdx.x;
        int level, m, chunk, S, SS2, lvloff;
        if (bid < 48)       { level = 0; m = bid;        chunk = 0;          S = 13; SS2 = 169;  lvloff = 0;    }
        else if (bid < 192) { level = 1; int q = bid-48; m = q / 3;  chunk = q - 3*m + 0;  S = 26; SS2 = 676;  lvloff = 507;
                              chunk = (q - 3*m); }
        else                { level = 2; int q = bid-192; m = q / 11; chunk = q - 11*m;    S = 52; SS2 = 2704; lvloff = 2535; }
        int b  = m / 3;
        int aa = m - 3 * b;
        int pos = chunk * 256 + tid;

        if (tid < S) s_cx[tid] = ((double)tid + 0.5) / (double)S;  // numpy-exact centers
        if (wid == 0) {   // wave 0 compacts this b's valid labels
            float cls = -1.0f, lbx = 0, lby = 0, lbw = 0, lbh = 0; int idx = -1;
            if (lane < LL) {
                const float* lab = labels + (b * LL + lane) * 5;
                cls = lab[0]; lbx = lab[1]; lby = lab[2]; lbw = lab[3]; lbh = lab[4];
                idx = idxArr[b * LL + lane];
            }
            bool valid = (lane < LL) && (cls >= 0.0f);
            unsigned long long mask = __ballot(valid);
            if (valid) {
                int p = __popcll(mask & ((1ull << lane) - 1ull));
                s_lbx[p] = lbx;
                s_lby[p] = lby;
                s_lxe[p] = __fadd_rn(lbx, lbw);
                s_lye[p] = __fadd_rn(lby, lbh);
                s_lar[p] = __fmul_rn(lbw, lbh);
                s_lidx[p] = idx;
            }
            if (lane == 0) s_lcnt = __popcll(mask);
        }
        __syncthreads();

        double a = 0.0;
        if (pos < SS2) {
            const float* outp = (level == 0) ? o0 : ((level == 1) ? o1 : o2);
            // coalesced: consecutive tid -> consecutive addresses
            float x = outp[((size_t)b * 255 + aa * 85 + 4) * SS2 + pos];
            int ii = pos / S, jj = pos - ii * S;
            int n  = lvloff + pos * 3 + aa;   // prior index
            float px  = (float)(s_cx[jj] - c_hw[level][aa]);
            float py  = (float)(s_cx[ii] - c_hh[level][aa]);
            float pwf = c_pwf[level][aa], phf = c_phf[level][aa];
            float pxe = __fadd_rn(px, pwf), pye = __fadd_rn(py, phf);
            float pwph = __fmul_rn(pwf, phf);
            bool supp = false, chosen = false;
            int cnt = s_lcnt;
            for (int l = 0; l < cnt; ++l) {   // LDS-broadcast reads, no conflicts
                chosen = chosen | (s_lidx[l] == n);
                float ix = fmaxf(px, s_lbx[l]);
                float iy = fmaxf(py, s_lby[l]);
                float ax = fminf(pxe, s_lxe[l]);
                float ay = fminf(pye, s_lye[l]);
                float iw = fmaxf(__fsub_rn(ax, ix), 0.0f);
                float ih = fmaxf(__fsub_rn(ay, iy), 0.0f);
                float inter = __fmul_rn(iw, ih);
                float denom = __fsub_rn(__fadd_rn(pwph, s_lar[l]), inter);
                supp = supp | ((double)inter >= SUPP_C * (double)denom);
            }
            if (chosen || !supp) {   // masked-out entries contribute exactly 0
                float p = 1.0f / (1.0f + expf(-x));
                float t = chosen ? 1.0f : 0.0f;
                float lp = fmaxf(logf(p), -100.0f);
                float lq = fmaxf(logf(1.0f - p), -100.0f);
                a = -(double)(t * lp + (1.0f - t) * lq) * c_wObj[level];
            }
        }
        s_red[tid] = a; __syncthreads();
        for (int s = 128; s > 0; s >>= 1) { if (tid < s) s_red[tid] += s_red[tid + s]; __syncthreads(); }
        if (tid == 0) pObj[bid] = s_red[0];
    } else {
        int gi = blockIdx.x - OBJ_BLOCKS;
        int b  = gi / LL, lsel = gi - b * LL;
        if (tid < LL) {
            s_cidx[tid] = idxArr[b * LL + tid];
            s_ccls[tid] = labels[(b * LL + tid) * 5];
        }
        __syncthreads();
        int sel = s_cidx[lsel];
        int maxl = -1;
        if (sel >= 0)
            for (int l = 0; l < LL; ++l) if (s_cidx[l] == sel) maxl = l;
        bool active = (sel >= 0) && (maxl == lsel);   // segment_max winner

        double vc = 0.0, vk = 0.0;
        if (active) {
            int level, S, ii, jj, aa, off;
            decode_prior(sel, level, S, ii, jj, aa, off);
            int SS2 = S * S;
            const float* outp = (level == 0) ? o0 : ((level == 1) ? o1 : o2);
            const float* base = outp + (size_t)b * 255 * SS2 + aa * 85 * SS2 + ii * S + jj;
            double wObj = c_wObj[level];
            if (tid < 4) {                     // coord channels 0..3
                float4 ct = tcoord[gi];
                float ctk = (tid == 0) ? ct.x : (tid == 1) ? ct.y : (tid == 2) ? ct.z : ct.w;
                float x = base[tid * SS2];
                float d = __fsub_rn(x, ctk);
                vc = (double)__fmul_rn(d, d) * (wObj * 0.25);
            } else if (tid >= 5 && tid < 85) { // class channels 5..84
                int cc = tid - 5;
                float x = base[tid * SS2];
                float t = 0.0f;
                for (int l = 0; l < LL; ++l)   // multi-hot over ALL labels mapping here
                    if (s_cidx[l] == sel && (int)s_ccls[l] == cc) t = 1.0f;
                float p = 1.0f / (1.0f + expf(-x));
                float lp = fmaxf(logf(p), -100.0f);
                float lq = fmaxf(logf(1.0f - p), -100.0f);
                vk = -(double)(t * lp + (1.0f - t) * lq) * (wObj * 0.0125);
            }
        }
        s_red[tid] = vc; __syncthreads();
        for (int s = 128; s > 0; s >>= 1) { if (tid < s) s_red[tid] += s_red[tid + s]; __syncthreads(); }
        if (tid == 0) pCoord[gi] = s_red[0];
        __syncthreads();
        s_red[tid] = vk; __syncthreads();
        for (int s = 128; s > 0; s >>= 1) { if (tid < s) s_red[tid] += s_red[tid + s]; __syncthreads(); }
        if (tid == 0) pClass[gi] = s_red[0];
    }
}

// ---------------------------------------------------------------- finalize (1 block, no atomics)
__global__ __launch_bounds__(256) void finalize_kernel(
    const double* __restrict__ pObj, const double* __restrict__ pCoord,
    const double* __restrict__ pClass, float* __restrict__ out) {
    int tid = threadIdx.x;
    double sO = 0.0, sC = 0.0, sK = 0.0;
    for (int i = tid; i < OBJ_BLOCKS; i += 256) sO += pObj[i];
    for (int i = tid; i < CHO_BLOCKS; i += 256) { sC += pCoord[i]; sK += pClass[i]; }
    __shared__ double r0[256], r1[256], r2[256];
    r0[tid] = sO; r1[tid] = sC; r2[tid] = sK;
    __syncthreads();
    for (int s = 128; s > 0; s >>= 1) {
        if (tid < s) { r0[tid] += r0[tid + s]; r1[tid] += r1[tid + s]; r2[tid] += r2[tid + s]; }
        __syncthreads();
    }
    if (tid == 0) { out[0] = (float)r0[0]; out[1] = (float)r1[0]; out[2] = (float)r2[0]; }
}

extern "C" void kernel_launch(void* const* d_in, const int* in_sizes, int n_in,
                              void* d_out, int out_size, void* d_ws, size_t ws_size,
                              hipStream_t stream) {
    const float* o0     = (const float*)d_in[0];
    const float* o1     = (const float*)d_in[1];
    const float* o2     = (const float*)d_in[2];
    const float* labels = (const float*)d_in[3];

    char* ws = (char*)d_ws;
    int*    idxArr = (int*)   (ws);          // 800*4  = 3200
    float4* tcoord = (float4*)(ws + 3200);   // 800*16 -> 16000
    double* pObj   = (double*)(ws + 16000);  // 720*8  -> 21760
    double* pCoord = (double*)(ws + 21760);  // 800*8  -> 28160
    double* pClass = (double*)(ws + 28160);  // 800*8  -> 34560

    assign_kernel<<<BB * LL, 256, 0, stream>>>(labels, idxArr, tcoord);
    loss_kernel<<<TOT_BLOCKS, 256, 0, stream>>>(o0, o1, o2, labels, idxArr, tcoord,
                                                pObj, pCoord, pClass);
    finalize_kernel<<<1, 256, 0, stream>>>(pObj, pCoord, pClass, (float*)d_out);
}

// Round 6
// 121.855 us; speedup vs baseline: 1.2683x; 1.0239x over previous
//
#include <hip/hip_runtime.h>

#define NPRI 10647
#define BB 16
#define LL 50
#define OBJ_BLOCKS 720          // 48 (L0) + 144 (L1) + 528 (L2) coalesced chunks
#define CHO_BLOCKS (BB * LL)    // 800
#define TOT_BLOCKS (OBJ_BLOCKS + CHO_BLOCKS)

// 0.5 - 2^-26: exact post-rounding threshold. round_rn(inter/denom) >= 0.5f
// <=> inter >= denom * SUPP_C (significand product exact in double; tie at
// 0.5-2^-26 rounds to even = 0.5 => suppressed). Validated rounds 4-5.
#define SUPP_C 0.49999998509883880615234375

// Anchor constants folded at COMPILE TIME, matching numpy's python-float math.
__device__ __constant__ double c_hw[3][3] = {
    {0.5*(116.0/416.0), 0.5*(156.0/416.0), 0.5*(373.0/416.0)},
    {0.5*( 30.0/416.0), 0.5*( 62.0/416.0), 0.5*( 59.0/416.0)},
    {0.5*( 10.0/416.0), 0.5*( 16.0/416.0), 0.5*( 33.0/416.0)}};
__device__ __constant__ double c_hh[3][3] = {
    {0.5*( 90.0/416.0), 0.5*(198.0/416.0), 0.5*(326.0/416.0)},
    {0.5*( 61.0/416.0), 0.5*( 45.0/416.0), 0.5*(119.0/416.0)},
    {0.5*( 23.0/416.0), 0.5*( 30.0/416.0), 0.5*( 23.0/416.0)}};
__device__ __constant__ float c_pwf[3][3] = {
    {(float)(116.0/416.0), (float)(156.0/416.0), (float)(373.0/416.0)},
    {(float)( 30.0/416.0), (float)( 62.0/416.0), (float)( 59.0/416.0)},
    {(float)( 10.0/416.0), (float)( 16.0/416.0), (float)( 33.0/416.0)}};
__device__ __constant__ float c_phf[3][3] = {
    {(float)( 90.0/416.0), (float)(198.0/416.0), (float)(326.0/416.0)},
    {(float)( 61.0/416.0), (float)( 45.0/416.0), (float)(119.0/416.0)},
    {(float)( 23.0/416.0), (float)( 30.0/416.0), (float)( 23.0/416.0)}};
// pw*ph folded at compile time (float x float, IEEE RN == __fmul_rn)
__device__ __constant__ float c_pwph[3][3] = {
    {(float)(116.0/416.0)*(float)( 90.0/416.0), (float)(156.0/416.0)*(float)(198.0/416.0), (float)(373.0/416.0)*(float)(326.0/416.0)},
    {(float)( 30.0/416.0)*(float)( 61.0/416.0), (float)( 62.0/416.0)*(float)( 45.0/416.0), (float)( 59.0/416.0)*(float)(119.0/416.0)},
    {(float)( 10.0/416.0)*(float)( 23.0/416.0), (float)( 16.0/416.0)*(float)( 30.0/416.0), (float)( 33.0/416.0)*(float)( 23.0/416.0)}};
__device__ __constant__ float c_awf[3][3] = {{116,156,373},{30,62,59},{10,16,33}};
__device__ __constant__ float c_ahf[3][3] = {{90,198,326},{61,45,119},{23,30,23}};
// 1 / (B*A*S*S) per level
__device__ __constant__ double c_wObj[3] = {1.0/8112.0, 1.0/32448.0, 1.0/129792.0};

// decode prior n -> level,S,ii,jj,aa and base of the 273-entry (level,aa,idx)
// prior table: L0 rows at 0, L1 at 39, L2 at 117. Constant divisors -> magic mul.
__device__ inline void decode_prior(int n, int& level, int& S, int& ii, int& jj,
                                    int& aa, int& tb) {
    if (n < 507)        { level = 0; S = 13; int c = n / 3;            aa = n - 3*c;            jj = c % 13; ii = c / 13; tb = 0;   }
    else if (n < 2535)  { level = 1; S = 26; int nn = n - 507;  int c = nn / 3; aa = nn - 3*c; jj = c % 26; ii = c / 26; tb = 39;  }
    else                { level = 2; S = 52; int nn = n - 2535; int c = nn / 3; aa = nn - 3*c; jj = c % 52; ii = c / 52; tb = 117; }
}

// ---------------------------------------------------------------- assign (one block per (b,l))
// Float prior tables in LDS (f64 math done once, not per prior); wave-shfl
// max-reduce and scan (3 barriers). Selection logic validated rounds 3-5.
__global__ __launch_bounds__(256) void assign_kernel(
    const float* __restrict__ labels, int* __restrict__ idxArr,
    float4* __restrict__ tcoord) {
    __shared__ float s_px[273], s_py[273], s_pxe[273], s_pye[273];
    __shared__ float s_iou[NPRI];  // 42.6 KB
    __shared__ float s_w[4];
    __shared__ int   s_wsum[4];

    int tid = threadIdx.x, lane = tid & 63, wid = tid >> 6;
    int gi  = blockIdx.x;
    const float* lab = labels + gi * 5;
    float cls = lab[0];
    if (tid == 0) idxArr[gi] = -1;
    if (cls < 0.0f) return;   // uniform per block, before any __syncthreads

    // prior tables: px/pxe indexed by jj, py/pye by ii (same table index form)
    for (int t = tid; t < 273; t += 256) {
        int level, aa, idx;
        if (t < 39)       { level = 0; aa = t / 13;           idx = t - 13 * aa; }
        else if (t < 117) { level = 1; int q = t - 39;  aa = q / 26; idx = q - 26 * aa; }
        else              { level = 2; int q = t - 117; aa = q / 52; idx = q - 52 * aa; }
        int S = (level == 0) ? 13 : (level == 1) ? 26 : 52;
        double c = ((double)idx + 0.5) / (double)S;           // numpy-exact
        float px = (float)(c - c_hw[level][aa]);
        float py = (float)(c - c_hh[level][aa]);
        s_px[t]  = px; s_pxe[t] = __fadd_rn(px, c_pwf[level][aa]);
        s_py[t]  = py; s_pye[t] = __fadd_rn(py, c_phf[level][aa]);
    }

    float bx = lab[1], by = lab[2], bw = lab[3], bh = lab[4];
    float bxe  = __fadd_rn(bx, bw), bye = __fadd_rn(by, bh);
    float bwbh = __fmul_rn(bw, bh);
    __syncthreads();

    float lmax = -3.0e38f;
    for (int n = tid; n < NPRI; n += 256) {
        int level, S, ii, jj, aa, tb;
        decode_prior(n, level, S, ii, jj, aa, tb);
        int tj = tb + aa * S + jj, ti = tb + aa * S + ii;
        float px = s_px[tj], pxe = s_pxe[tj];
        float py = s_py[ti], pye = s_pye[ti];
        float pwph = c_pwph[level][aa];
        float ix = fmaxf(px, bx), iy = fmaxf(py, by);
        float ax = fminf(pxe, bxe), ay = fminf(pye, bye);
        float iw = fmaxf(__fsub_rn(ax, ix), 0.0f);
        float ih = fmaxf(__fsub_rn(ay, iy), 0.0f);
        float inter = __fmul_rn(iw, ih);
        float denom = __fsub_rn(__fadd_rn(pwph, bwbh), inter);
        float iou = __fdiv_rn(inter, denom);
        s_iou[n] = iou;
        lmax = fmaxf(lmax, iou);
    }
    // wave-level max reduce (6 shfl steps), then 4-way LDS combine
    for (int d = 1; d < 64; d <<= 1) lmax = fmaxf(lmax, __shfl_xor(lmax, d));
    if (lane == 0) s_w[wid] = lmax;
    __syncthreads();   // also publishes s_iou
    float m = fmaxf(fmaxf(s_w[0], s_w[1]), fmaxf(s_w[2], s_w[3]));

    // tie count per contiguous chunk (index order)
    const int CH = 42;   // 256*42 >= NPRI
    int start = tid * CH;
    int end   = min(start + CH, NPRI);
    int cnt = 0;
    for (int n = start; n < end; ++n) cnt += (s_iou[n] == m) ? 1 : 0;

    // wave-level inclusive scan (shfl_up), wave offsets via LDS
    int incl = cnt;
    for (int d = 1; d < 64; d <<= 1) {
        int v = __shfl_up(incl, d);
        if (lane >= d) incl += v;
    }
    if (lane == 63) s_wsum[wid] = incl;
    __syncthreads();
    int woff = 0, k = 0;
    for (int w = 0; w < 4; ++w) { int v = s_wsum[w]; k += v; if (w < wid) woff += v; }
    int rank = (k - 1) / 2 + 1;
    int pre  = woff + incl - cnt;   // exclusive prefix

    if (pre < rank && rank <= pre + cnt) {
        int r = rank - pre;
        int sel = -1;
        for (int n = start; n < end; ++n)
            if (s_iou[n] == m && --r == 0) { sel = n; break; }
        int level, S, ii, jj, aa, tb;
        decode_prior(sel, level, S, ii, jj, aa, tb);
        float Sf = (float)S, colf = (float)jj, rowf = (float)ii;
        float dx = __fsub_rn(__fmul_rn(__fadd_rn(bx, __fmul_rn(0.5f, bw)), Sf), colf);
        float dy = __fsub_rn(__fmul_rn(__fadd_rn(by, __fmul_rn(0.5f, bh)), Sf), rowf);
        dx = fminf(fmaxf(dx, 1e-6f), 0.999999f);
        dy = fminf(fmaxf(dy, 1e-6f), 0.999999f);
        float t0 = logf(__fdiv_rn(dx, __fsub_rn(1.0f, dx)));
        float t1 = logf(__fdiv_rn(dy, __fsub_rn(1.0f, dy)));
        float t2 = logf(__fdiv_rn(__fmul_rn(bw, 416.0f), c_awf[level][aa]));
        float t3 = logf(__fdiv_rn(__fmul_rn(bh, 416.0f), c_ahf[level][aa]));
        tcoord[gi] = make_float4(t0, t1, t2, t3);
        idxArr[gi] = sel;
    }
}

// ---------------------------------------------------------------- fused loss
// blocks [0, OBJ_BLOCKS): obj BCE in memory order — one block per
//   (level, b, anchor, 256-span). Coalesced channel reads; per-block S-entry
//   float prior tables (level,aa fixed per block); exact div-free supp test.
// blocks [OBJ_BLOCKS, TOT_BLOCKS): coord+class for label gi, lane-parallel.
__global__ __launch_bounds__(256) void loss_kernel(
    const float* __restrict__ o0, const float* __restrict__ o1, const float* __restrict__ o2,
    const float* __restrict__ labels, const int* __restrict__ idxArr,
    const float4* __restrict__ tcoord,
    double* __restrict__ pObj, double* __restrict__ pCoord, double* __restrict__ pClass) {
    __shared__ float  s_pxv[52], s_pyv[52], s_pxev[52], s_pyev[52];
    __shared__ float  s_lbx[LL], s_lby[LL], s_lxe[LL], s_lye[LL], s_lar[LL];
    __shared__ int    s_lidx[LL];
    __shared__ int    s_lcnt;
    __shared__ int    s_cidx[LL];
    __shared__ float  s_ccls[LL];
    __shared__ double s_red[256];
    int tid = threadIdx.x, lane = tid & 63, wid = tid >> 6;

    if (blockIdx.x < OBJ_BLOCKS) {
        // ---- decode (level, b, aa, chunk)
        int bid = blockIdx.x;
        int level, m, chunk, S, SS2, lvloff;
        if (bid < 48)       { level = 0; m = bid;         chunk = 0;           S = 13; SS2 = 169;  lvloff = 0;    }
        else if (bid < 192) { level = 1; int q = bid-48;  m = q / 3;  chunk = q - 3*m;  S = 26; SS2 = 676;  lvloff = 507;  }
        else                { level = 2; int q = bid-192; m = q / 11; chunk = q - 11*m; S = 52; SS2 = 2704; lvloff = 2535; }
        int b  = m / 3;
        int aa = m - 3 * b;
        int pos = chunk * 256 + tid;

        if (tid < S) {   // per-block prior tables (level, aa fixed)
            double c = ((double)tid + 0.5) / (double)S;   // numpy-exact centers
            float px = (float)(c - c_hw[level][aa]);
            float py = (float)(c - c_hh[level][aa]);
            s_pxv[tid]  = px; s_pxev[tid] = __fadd_rn(px, c_pwf[level][aa]);
            s_pyv[tid]  = py; s_pyev[tid] = __fadd_rn(py, c_phf[level][aa]);
        }
        if (wid == 0) {   // wave 0 compacts this b's valid labels
            float cls = -1.0f, lbx = 0, lby = 0, lbw = 0, lbh = 0; int idx = -1;
            if (lane < LL) {
                const float* lab = labels + (b * LL + lane) * 5;
                cls = lab[0]; lbx = lab[1]; lby = lab[2]; lbw = lab[3]; lbh = lab[4];
                idx = idxArr[b * LL + lane];
            }
            bool valid = (lane < LL) && (cls >= 0.0f);
            unsigned long long mask = __ballot(valid);
            if (valid) {
                int p = __popcll(mask & ((1ull << lane) - 1ull));
                s_lbx[p] = lbx;
                s_lby[p] = lby;
                s_lxe[p] = __fadd_rn(lbx, lbw);
                s_lye[p] = __fadd_rn(lby, lbh);
                s_lar[p] = __fmul_rn(lbw, lbh);
                s_lidx[p] = idx;
            }
            if (lane == 0) s_lcnt = __popcll(mask);
        }
        __syncthreads();

        double a = 0.0;
        if (pos < SS2) {
            const float* outp = (level == 0) ? o0 : ((level == 1) ? o1 : o2);
            // coalesced: consecutive tid -> consecutive addresses
            float x = outp[((size_t)b * 255 + aa * 85 + 4) * SS2 + pos];
            int ii = pos / S, jj = pos - ii * S;
            int n  = lvloff + pos * 3 + aa;   // prior index
            float px = s_pxv[jj], pxe = s_pxev[jj];
            float py = s_pyv[ii], pye = s_pyev[ii];
            float pwph = c_pwph[level][aa];
            bool supp = false, chosen = false;
            int cnt = s_lcnt;
            for (int l = 0; l < cnt; ++l) {   // LDS-broadcast reads, no conflicts
                chosen = chosen | (s_lidx[l] == n);
                float ix = fmaxf(px, s_lbx[l]);
                float iy = fmaxf(py, s_lby[l]);
                float ax = fminf(pxe, s_lxe[l]);
                float ay = fminf(pye, s_lye[l]);
                float iw = fmaxf(__fsub_rn(ax, ix), 0.0f);
                float ih = fmaxf(__fsub_rn(ay, iy), 0.0f);
                float inter = __fmul_rn(iw, ih);
                float denom = __fsub_rn(__fadd_rn(pwph, s_lar[l]), inter);
                supp = supp | ((double)inter >= SUPP_C * (double)denom);
            }
            if (chosen || !supp) {   // masked-out entries contribute exactly 0
                float p = 1.0f / (1.0f + expf(-x));
                float t = chosen ? 1.0f : 0.0f;
                float lp = fmaxf(logf(p), -100.0f);
                float lq = fmaxf(logf(1.0f - p), -100.0f);
                a = -(double)(t * lp + (1.0f - t) * lq) * c_wObj[level];
            }
        }
        s_red[tid] = a; __syncthreads();
        for (int s = 128; s > 0; s >>= 1) { if (tid < s) s_red[tid] += s_red[tid + s]; __syncthreads(); }
        if (tid == 0) pObj[bid] = s_red[0];
    } else {
        int gi = blockIdx.x - OBJ_BLOCKS;
        int b  = gi / LL, lsel = gi - b * LL;
        if (tid < LL) {
            s_cidx[tid] = idxArr[b * LL + tid];
            s_ccls[tid] = labels[(b * LL + tid) * 5];
        }
        __syncthreads();
        int sel = s_cidx[lsel];
        int maxl = -1;
        if (sel >= 0)
            for (int l = 0; l < LL; ++l) if (s_cidx[l] == sel) maxl = l;
        bool active = (sel >= 0) && (maxl == lsel);   // segment_max winner

        double vc = 0.0, vk = 0.0;
        if (active) {
            int level, S, ii, jj, aa, tb;
            decode_prior(sel, level, S, ii, jj, aa, tb);
            int SS2 = S * S;
            const float* outp = (level == 0) ? o0 : ((level == 1) ? o1 : o2);
            const float* base = outp + (size_t)b * 255 * SS2 + aa * 85 * SS2 + ii * S + jj;
            double wObj = c_wObj[level];
            if (tid < 4) {                     // coord channels 0..3
                float4 ct = tcoord[gi];
                float ctk = (tid == 0) ? ct.x : (tid == 1) ? ct.y : (tid == 2) ? ct.z : ct.w;
                float x = base[tid * SS2];
                float d = __fsub_rn(x, ctk);
                vc = (double)__fmul_rn(d, d) * (wObj * 0.25);
            } else if (tid >= 5 && tid < 85) { // class channels 5..84
                int cc = tid - 5;
                float x = base[tid * SS2];
                float t = 0.0f;
                for (int l = 0; l < LL; ++l)   // multi-hot over ALL labels mapping here
                    if (s_cidx[l] == sel && (int)s_ccls[l] == cc) t = 1.0f;
                float p = 1.0f / (1.0f + expf(-x));
                float lp = fmaxf(logf(p), -100.0f);
                float lq = fmaxf(logf(1.0f - p), -100.0f);
                vk = -(double)(t * lp + (1.0f - t) * lq) * (wObj * 0.0125);
            }
        }
        s_red[tid] = vc; __syncthreads();
        for (int s = 128; s > 0; s >>= 1) { if (tid < s) s_red[tid] += s_red[tid + s]; __syncthreads(); }
        if (tid == 0) pCoord[gi] = s_red[0];
        __syncthreads();
        s_red[tid] = vk; __syncthreads();
        for (int s = 128; s > 0; s >>= 1) { if (tid < s) s_red[tid] += s_red[tid + s]; __syncthreads(); }
        if (tid == 0) pClass[gi] = s_red[0];
    }
}

// ---------------------------------------------------------------- finalize (1 block, no atomics)
__global__ __launch_bounds__(256) void finalize_kernel(
    const double* __restrict__ pObj, const double* __restrict__ pCoord,
    const double* __restrict__ pClass, float* __restrict__ out) {
    int tid = threadIdx.x;
    double sO = 0.0, sC = 0.0, sK = 0.0;
    for (int i = tid; i < OBJ_BLOCKS; i += 256) sO += pObj[i];
    for (int i = tid; i < CHO_BLOCKS; i += 256) { sC += pCoord[i]; sK += pClass[i]; }
    __shared__ double r0[256], r1[256], r2[256];
    r0[tid] = sO; r1[tid] = sC; r2[tid] = sK;
    __syncthreads();
    for (int s = 128; s > 0; s >>= 1) {
        if (tid < s) { r0[tid] += r0[tid + s]; r1[tid] += r1[tid + s]; r2[tid] += r2[tid + s]; }
        __syncthreads();
    }
    if (tid == 0) { out[0] = (float)r0[0]; out[1] = (float)r1[0]; out[2] = (float)r2[0]; }
}

extern "C" void kernel_launch(void* const* d_in, const int* in_sizes, int n_in,
                              void* d_out, int out_size, void* d_ws, size_t ws_size,
                              hipStream_t stream) {
    const float* o0     = (const float*)d_in[0];
    const float* o1     = (const float*)d_in[1];
    const float* o2     = (const float*)d_in[2];
    const float* labels = (const float*)d_in[3];

    char* ws = (char*)d_ws;
    int*    idxArr = (int*)   (ws);          // 800*4  = 3200
    float4* tcoord = (float4*)(ws + 3200);   // 800*16 -> 16000
    double* pObj   = (double*)(ws + 16000);  // 720*8  -> 21760
    double* pCoord = (double*)(ws + 21760);  // 800*8  -> 28160
    double* pClass = (double*)(ws + 28160);  // 800*8  -> 34560

    assign_kernel<<<BB * LL, 256, 0, stream>>>(labels, idxArr, tcoord);
    loss_kernel<<<TOT_BLOCKS, 256, 0, stream>>>(o0, o1, o2, labels, idxArr, tcoord,
                                                pObj, pCoord, pClass);
    finalize_kernel<<<1, 256, 0, stream>>>(pObj, pCoord, pClass, (float*)d_out);
}